// Round 18
// baseline (94.153 us; speedup 1.0000x reference)
//
#include <hip/hip_runtime.h>
#include <hip/hip_bf16.h>

// BatchedNeRFMLP: B=64, N=16384, HID=128, POS_IN=63 (+bias col -> K=64), DIR_IN=27
// params per batch (TOTAL=8789 fp32):
//   pw [128][63] @0   pb[128]@8064   sw[128]@8192  sb@8320
//   cw [3][155] @8321 cb[3]@8786
// out: sigma (B*N) then rgb (B*N*3), fp32.
//
// r16/r17 structure (45.9us best, 3 blocks/CU) + VALU chunks moved INTO the
// unroll-1 mt loop: r16's unroll-1 made each mt a basic block, so the
// compiler could no longer interleave the pre-loop dir-tail/encode VALU into
// MFMA shadows (r15 proved that interleave exists in a flat body). Chunks are
// placed after the 8 L1 MFMAs (awf dead, a0/a1 in flight), before repack:
//   mt==0 -> full dir-tail (~110 ops)   mt==2 -> full encode(it+1) (~105 ops)
// No state carried across mt iters beyond crd/cgd/cbd -> no reg-pressure rise.
// DS order: all be reads precede the loop; encode writes at mt==2 follow them.
// Occupancy recipe (r8/r10/r16): aw in LDS shared, mt unroll-1 (awf 16 regs),
// arch ~76 <= 84, acc 80 <= 84 at (256,3). LDS 49KB x 3 = 147 <= 160KB.
// Balanced grid 768 = 3 blocks/CU, zero tail [r17]. Tripwire: WRITE >> 16MB.

#define NB 64
#define NRAY 16384
#define NTOTAL 8789

typedef short bf16x8 __attribute__((ext_vector_type(8)));
typedef float f32x16 __attribute__((ext_vector_type(16)));

union U8 { unsigned u[4]; bf16x8 v; };

__device__ __forceinline__ unsigned pk2(float a, float b) {
    float2 t; t.x = a; t.y = b;
    __hip_bfloat162 h = __float22bfloat162_rn(t);   // v_cvt_pk_bf16_f32
    return *reinterpret_cast<unsigned*>(&h);
}

#define MFMA __builtin_amdgcn_mfma_f32_32x32x16_bf16

__global__ __launch_bounds__(256, 3) void nerf_mfma_kernel(
    const float* __restrict__ pos,
    const float* __restrict__ dir,
    const float* __restrict__ params,
    float* __restrict__ out)
{
    const int tid  = threadIdx.x;
    const int lane = tid & 63;
    const int wid  = tid >> 6;
    const int hi   = lane >> 5;
    const int l31  = lane & 31;

    // 12 blocks per batch; first 4 take 6 chunk-iters, rest take 5 (4*6+8*5=64)
    const int b   = blockIdx.x / 12;
    const int j   = blockIdx.x - b * 12;
    const int nit = (j < 4) ? 6 : 5;
    const int startChunk = (j < 4) ? j * 6 : 24 + (j - 4) * 5;
    const int chunk = startChunk << 8;          // *256 rays
    const float* __restrict__ p = params + b * NTOTAL;

    __shared__ uint4 encs[2048];                // 256 rows x 128B, swizzled
    __shared__ uint4 awT[1024];                 // 128 rows x 128B, swizzled
    __shared__ unsigned hawLds[256];            // [s][hi][r][4 words] = 1KB
    char* encb = reinterpret_cast<char*>(encs);
    const char* awb  = reinterpret_cast<const char*>(awT);
    const char* hawb = reinterpret_cast<const char*>(hawLds);

    // ---- head-weight fragments into LDS (one-time, 64 threads) ------------
    // K permuted: slot(s,hh,i) -> h = 32*(s>>1)+16*(s&1)+4*hh+(i&3)+8*(i>>2)
    if (tid < 64) {
        const int s  = tid & 7;
        const int hh = (tid >> 3) & 1;
        const int r  = tid >> 4;                // 0=sigma(sw), 1..3 = cw rows
        const float* w2 = (r == 0) ? (p + 8192) : (p + 8321 + (r - 1) * 155);
        const int base = 32 * (s >> 1) + 16 * (s & 1) + 4 * hh;
        unsigned* dst = &hawLds[(((s << 1) + hh) * 4 + r) * 4];
        #pragma unroll
        for (int jj = 0; jj < 4; ++jj) {
            const int i0 = 2 * jj, i1 = 2 * jj + 1;
            dst[jj] = pk2(w2[base + (i0 & 3) + 8 * (i0 >> 2)],
                          w2[base + (i1 & 3) + 8 * (i1 >> 2)]);
        }
    }

    // ---- layer-1 A tile into LDS (one-time, shared by all waves) ----------
    // K-order: k<3 -> pw[h][k]; k==3 -> pb[h]; k>=4 -> pw[h][k-1]
    {
        const int h    = tid >> 1;              // 0..127
        const int half = tid & 1;
        const float* wrow = p + h * 63;
        const float bias  = p[8064 + h];
        char* dst = reinterpret_cast<char*>(awT) + h * 128;
        const int swz = (h & 7) << 4;
        #pragma unroll
        for (int c4 = 0; c4 < 4; ++c4) {
            const int c = half * 4 + c4;
            U8 u;
            #pragma unroll
            for (int jj = 0; jj < 4; ++jj) {
                const int k0 = 8 * c + 2 * jj, k1 = k0 + 1;
                const float e0 = (k0 < 3) ? wrow[k0] : (k0 == 3 ? bias : wrow[k0 - 1]);
                const float e1 = (k1 < 3) ? wrow[k1] : (k1 == 3 ? bias : wrow[k1 - 1]);
                u.u[jj] = pk2(e0, e1);
            }
            *reinterpret_cast<uint4*>(dst + ((c * 16) ^ swz)) =
                *reinterpret_cast<uint4*>(&u);
        }
    }

    f32x16 FZ;
    #pragma unroll
    for (int i = 0; i < 16; ++i) FZ[i] = 0.f;

    const float sb  = p[8320];
    const float cb0 = p[8786], cb1 = p[8787], cb2 = p[8788];
    const float* __restrict__ cwr  = p + 8321 + 128;
    const float* __restrict__ cwg  = p + 8321 + 155 + 128;
    const float* __restrict__ cwb2 = p + 8321 + 310 + 128;

    const int rayBlock = b * NRAY + chunk;
    float* __restrict__ rgbout = out + (long)NB * NRAY;
    const long pb0 = (long)(rayBlock + tid) * 3;
    const int hoff = hi * 64 + (l31 & 3) * 16;

    // ---- pos encoding into row `tid` (prologue only; in-loop is chunked) ---
    auto encode_row = [&](const float3 Pv) {
        const int swz = (tid & 7) << 4;
        char* myrow = encb + tid * 128;
        float s0 = __builtin_amdgcn_sinf(0.5f * Pv.x), c0 = __builtin_amdgcn_cosf(0.5f * Pv.x);
        float s1 = __builtin_amdgcn_sinf(0.5f * Pv.y), c1 = __builtin_amdgcn_cosf(0.5f * Pv.y);
        float s2 = __builtin_amdgcn_sinf(0.5f * Pv.z), c2 = __builtin_amdgcn_cosf(0.5f * Pv.z);
        unsigned wb[4];
        wb[0] = pk2(Pv.x, Pv.y);
        wb[1] = pk2(Pv.z, 1.0f);
        #pragma unroll
        for (int f = 0; f < 10; ++f) {
            const int w = 2 + 3 * f;
            wb[(w + 0) & 3] = pk2(s0, s1);
            if (((w + 0) & 3) == 3) {
                uint4 v; v.x = wb[0]; v.y = wb[1]; v.z = wb[2]; v.w = wb[3];
                *reinterpret_cast<uint4*>(myrow + ((((w + 0) >> 2) * 16) ^ swz)) = v;
            }
            wb[(w + 1) & 3] = pk2(s2, c0);
            if (((w + 1) & 3) == 3) {
                uint4 v; v.x = wb[0]; v.y = wb[1]; v.z = wb[2]; v.w = wb[3];
                *reinterpret_cast<uint4*>(myrow + ((((w + 1) >> 2) * 16) ^ swz)) = v;
            }
            wb[(w + 2) & 3] = pk2(c1, c2);
            if (((w + 2) & 3) == 3) {
                uint4 v; v.x = wb[0]; v.y = wb[1]; v.z = wb[2]; v.w = wb[3];
                *reinterpret_cast<uint4*>(myrow + ((((w + 2) >> 2) * 16) ^ swz)) = v;
            }
            if (f < 9) {
                float t;
                t = 2.f * s0 * c0; c0 = fmaf(-2.f * s0, s0, 1.f); s0 = t;
                t = 2.f * s1 * c1; c1 = fmaf(-2.f * s1, s1, 1.f); s1 = t;
                t = 2.f * s2 * c2; c2 = fmaf(-2.f * s2, s2, 1.f); s2 = t;
            }
        }
    };

    // prologue: current inputs + iter-1 prefetch, encode iter-0
    float3 Pc = *reinterpret_cast<const float3*>(pos + pb0);
    float3 Dc = *reinterpret_cast<const float3*>(dir + pb0);
    encode_row(Pc);
    float3 Pn = *reinterpret_cast<const float3*>(pos + pb0 + 768);
    float3 Dn = *reinterpret_cast<const float3*>(dir + pb0 + 768);
    __syncthreads();    // awT + hawLds ready (encs rows are wave-private)

    #pragma unroll 1
    for (int it = 0; it < nit; ++it) {
        const int ray = rayBlock + it * 256 + tid;

        // ---- all 8 B-frag reads first (rows hold enc(it)) ------------------
        bf16x8 be0[4], be1[4];
        {
            const int row0 = wid * 64 + l31;
            const int swz0 = (row0 & 7) << 4;
            const int row1 = row0 + 32;
            const int swz1 = (row1 & 7) << 4;
            #pragma unroll
            for (int ks = 0; ks < 4; ++ks) {
                be0[ks] = *reinterpret_cast<const bf16x8*>(
                    encb + row0 * 128 + ((ks * 32 + hi * 16) ^ swz0));
                be1[ks] = *reinterpret_cast<const bf16x8*>(
                    encb + row1 * 128 + ((ks * 32 + hi * 16) ^ swz1));
            }
        }

        // ---- prefetch inputs for it+2 (rotate at iter end) ------------------
        float3 Pn2, Dn2;
        if (it < nit - 2) {
            Pn2 = *reinterpret_cast<const float3*>(pos + pb0 + (it + 2) * 768);
            Dn2 = *reinterpret_cast<const float3*>(dir + pb0 + (it + 2) * 768);
        }

        // ---- MFMA region with in-loop VALU chunks ---------------------------
        float crd = 0.f, cgd = 0.f, cbd = 0.f;

        __builtin_amdgcn_s_setprio(1);
        f32x16 hacc0 = FZ, hacc1 = FZ;
        #pragma unroll 1
        for (int mt = 0; mt < 4; ++mt) {
            const int arow = (mt << 5) + l31;
            const int aswz = (arow & 7) << 4;
            const char* abase = awb + arow * 128;
            const bf16x8 awf0 = *reinterpret_cast<const bf16x8*>(abase + ((0  + hi * 16) ^ aswz));
            const bf16x8 awf1 = *reinterpret_cast<const bf16x8*>(abase + ((32 + hi * 16) ^ aswz));
            const bf16x8 awf2 = *reinterpret_cast<const bf16x8*>(abase + ((64 + hi * 16) ^ aswz));
            const bf16x8 awf3 = *reinterpret_cast<const bf16x8*>(abase + ((96 + hi * 16) ^ aswz));

            f32x16 a0 = MFMA(awf0, be0[0], FZ, 0, 0, 0);
            f32x16 a1 = MFMA(awf0, be1[0], FZ, 0, 0, 0);
            a0 = MFMA(awf1, be0[1], a0, 0, 0, 0);
            a1 = MFMA(awf1, be1[1], a1, 0, 0, 0);
            a0 = MFMA(awf2, be0[2], a0, 0, 0, 0);
            a1 = MFMA(awf2, be1[2], a1, 0, 0, 0);
            a0 = MFMA(awf3, be0[3], a0, 0, 0, 0);
            a1 = MFMA(awf3, be1[3], a1, 0, 0, 0);

            // ---- independent VALU chunk in the L1-MFMA shadow (awf dead) ----
            if (mt == 0) {          // full dir-tail dot for this iter
                float s0 = __builtin_amdgcn_sinf(0.5f * Dc.x), c0 = __builtin_amdgcn_cosf(0.5f * Dc.x);
                float s1 = __builtin_amdgcn_sinf(0.5f * Dc.y), c1 = __builtin_amdgcn_cosf(0.5f * Dc.y);
                float s2 = __builtin_amdgcn_sinf(0.5f * Dc.z), c2 = __builtin_amdgcn_cosf(0.5f * Dc.z);
                crd = fmaf(Dc.x, cwr[0], crd);  cgd = fmaf(Dc.x, cwg[0], cgd);  cbd = fmaf(Dc.x, cwb2[0], cbd);
                crd = fmaf(Dc.y, cwr[1], crd);  cgd = fmaf(Dc.y, cwg[1], cgd);  cbd = fmaf(Dc.y, cwb2[1], cbd);
                crd = fmaf(Dc.z, cwr[2], crd);  cgd = fmaf(Dc.z, cwg[2], cgd);  cbd = fmaf(Dc.z, cwb2[2], cbd);
                #pragma unroll
                for (int f = 0; f < 4; ++f) {
                    const int jj = 3 + 6 * f;
                    crd = fmaf(s0, cwr[jj+0], crd); cgd = fmaf(s0, cwg[jj+0], cgd); cbd = fmaf(s0, cwb2[jj+0], cbd);
                    crd = fmaf(s1, cwr[jj+1], crd); cgd = fmaf(s1, cwg[jj+1], cgd); cbd = fmaf(s1, cwb2[jj+1], cbd);
                    crd = fmaf(s2, cwr[jj+2], crd); cgd = fmaf(s2, cwg[jj+2], cgd); cbd = fmaf(s2, cwb2[jj+2], cbd);
                    crd = fmaf(c0, cwr[jj+3], crd); cgd = fmaf(c0, cwg[jj+3], cgd); cbd = fmaf(c0, cwb2[jj+3], cbd);
                    crd = fmaf(c1, cwr[jj+4], crd); cgd = fmaf(c1, cwg[jj+4], cgd); cbd = fmaf(c1, cwb2[jj+4], cbd);
                    crd = fmaf(c2, cwr[jj+5], crd); cgd = fmaf(c2, cwg[jj+5], cgd); cbd = fmaf(c2, cwb2[jj+5], cbd);
                    if (f < 3) {
                        float t;
                        t = 2.f * s0 * c0; c0 = fmaf(-2.f * s0, s0, 1.f); s0 = t;
                        t = 2.f * s1 * c1; c1 = fmaf(-2.f * s1, s1, 1.f); s1 = t;
                        t = 2.f * s2 * c2; c2 = fmaf(-2.f * s2, s2, 1.f); s2 = t;
                    }
                }
            }
            if (mt == 2 && it < nit - 1) {   // full encode(it+1)
                encode_row(Pn);
            }

            // ---- relu -> pack own regs, head MFMAs (consume a0/a1) ----------
            #pragma unroll
            for (int t = 0; t < 2; ++t) {
                const int rb = t * 8;
                U8 u0, u1;
                #pragma unroll
                for (int jj = 0; jj < 4; ++jj) {
                    u0.u[jj] = pk2(fmaxf(a0[rb + 2 * jj], 0.f),
                                   fmaxf(a0[rb + 2 * jj + 1], 0.f));
                    u1.u[jj] = pk2(fmaxf(a1[rb + 2 * jj], 0.f),
                                   fmaxf(a1[rb + 2 * jj + 1], 0.f));
                }
                const bf16x8 hw = *reinterpret_cast<const bf16x8*>(
                    hawb + (2 * mt + t) * 128 + hoff);
                hacc0 = MFMA(hw, u0.v, hacc0, 0, 0, 0);
                hacc1 = MFMA(hw, u1.v, hacc1, 0, 0, 0);
            }
        }
        __builtin_amdgcn_s_setprio(0);

        // ---- per-ray tail: select + bias + dir partial + sigmoid -----------
        const float hv0 = hi ? hacc1[0] : hacc0[0];
        const float hv1 = hi ? hacc1[1] : hacc0[1];
        const float hv2 = hi ? hacc1[2] : hacc0[2];
        const float hv3 = hi ? hacc1[3] : hacc0[3];

        const float sig = hv0 + sb;
        float cr  = hv1 + cb0 + crd;
        float cg  = hv2 + cb1 + cgd;
        float cbl = hv3 + cb2 + cbd;

        cr  = 1.0f / (1.0f + __expf(-cr));
        cg  = 1.0f / (1.0f + __expf(-cg));
        cbl = 1.0f / (1.0f + __expf(-cbl));

        out[ray] = sig;
        float3 rgbv; rgbv.x = cr; rgbv.y = cg; rgbv.z = cbl;
        *reinterpret_cast<float3*>(rgbout + (long)ray * 3) = rgbv;

        Pn = Pn2; Dc = Dn; Dn = Dn2;
    }
}

extern "C" void kernel_launch(void* const* d_in, const int* in_sizes, int n_in,
                              void* d_out, int out_size, void* d_ws, size_t ws_size,
                              hipStream_t stream) {
    const float* pos    = (const float*)d_in[0];
    const float* dirs   = (const float*)d_in[1];
    const float* params = (const float*)d_in[2];
    float* out = (float*)d_out;

    dim3 grid(768);    // 12 blocks/batch x 64 batches; exactly 3 blocks/CU
    dim3 block(256);
    nerf_mfma_kernel<<<grid, block, 0, stream>>>(pos, dirs, params, out);
}

// Round 19
// 44.807 us; speedup vs baseline: 2.1013x; 2.1013x over previous
//
#include <hip/hip_runtime.h>
#include <hip/hip_bf16.h>

// BatchedNeRFMLP: B=64, N=16384, HID=128, POS_IN=63 (+bias col -> K=64), DIR_IN=27
// params per batch (TOTAL=8789 fp32):
//   pw [128][63] @0   pb[128]@8064   sw[128]@8192  sb@8320
//   cw [3][155] @8321 cb[3]@8786
// out: sigma (B*N) then rgb (B*N*3), fp32.
//
// r16 structure (45.9us best: 3 blocks/CU via aw-in-LDS + mt unroll-1) with
// FRAGMENT-LINEAR LDS layout replacing row-major+XOR:
//   r16's row-stride-128B tiles put a wave's 32 row-reads on 8 of 32 banks ->
//   4-way conflict (1.63M conflict cycles). New layout stores each MFMA
//   fragment's 64 lane-chunks consecutively: block[frag]*1024 + lane*16.
//   All 24 reads + 8 writes per iter become consecutive-address = conflict-free.
//   ENC: block (wid*2+nt)*4+ks, chunk idx = hi*32+l31 (reader lane).
//   A:   block mt*4+ks, chunk = lane. haw unchanged (broadcast reads are free).
// In-loop VALU chunking REJECTED (r15 neutral flat, r18 spill in-loop): dir
// tail + encode stay pre-loop [r16 position]. (256,3) recipe: aw shared in
// LDS, mt loop unroll-1 (awf 16 regs live), arch ~76 <= 84, acc 80 <= 84.
// Tripwire: WRITE_SIZE >> 16MB = spill = revert.
// Trig: v_sin/v_cos take REVOLUTIONS -> sin(pi x) = builtin_sinf(0.5x).

#define NB 64
#define NRAY 16384
#define NTOTAL 8789
#define NIT 4

typedef short bf16x8 __attribute__((ext_vector_type(8)));
typedef float f32x16 __attribute__((ext_vector_type(16)));

union U8 { unsigned u[4]; bf16x8 v; };

__device__ __forceinline__ unsigned pk2(float a, float b) {
    float2 t; t.x = a; t.y = b;
    __hip_bfloat162 h = __float22bfloat162_rn(t);   // v_cvt_pk_bf16_f32
    return *reinterpret_cast<unsigned*>(&h);
}

#define MFMA __builtin_amdgcn_mfma_f32_32x32x16_bf16

__global__ __launch_bounds__(256, 3) void nerf_mfma_kernel(
    const float* __restrict__ pos,
    const float* __restrict__ dir,
    const float* __restrict__ params,
    float* __restrict__ out)
{
    const int tid  = threadIdx.x;
    const int lane = tid & 63;
    const int wid  = tid >> 6;
    const int hi   = lane >> 5;
    const int l31  = lane & 31;

    const int b     = blockIdx.x >> 4;          // 16 blocks per batch
    const int chunk = (blockIdx.x & 15) << 10;  // 1024 rays per block
    const float* __restrict__ p = params + b * NTOTAL;

    // fragment-linear tiles: [block][chunk16B]; 1024B per fragment-block
    __shared__ uint4 encs[2048];                // 32 blocks x 64 chunks = 32KB
    __shared__ uint4 awT[1024];                 // 16 blocks x 64 chunks = 16KB
    __shared__ unsigned hawLds[256];            // [s][hi][r][4 words] = 1KB
    char* encb = reinterpret_cast<char*>(encs);
    const char* awb  = reinterpret_cast<const char*>(awT);
    const char* hawb = reinterpret_cast<const char*>(hawLds);

    // ---- head-weight fragments into LDS (one-time, 64 threads) ------------
    // K permuted: slot(s,hh,i) -> h = 32*(s>>1)+16*(s&1)+4*hh+(i&3)+8*(i>>2)
    if (tid < 64) {
        const int s  = tid & 7;
        const int hh = (tid >> 3) & 1;
        const int r  = tid >> 4;                // 0=sigma(sw), 1..3 = cw rows
        const float* w2 = (r == 0) ? (p + 8192) : (p + 8321 + (r - 1) * 155);
        const int base = 32 * (s >> 1) + 16 * (s & 1) + 4 * hh;
        unsigned* dst = &hawLds[(((s << 1) + hh) * 4 + r) * 4];
        #pragma unroll
        for (int jj = 0; jj < 4; ++jj) {
            const int i0 = 2 * jj, i1 = 2 * jj + 1;
            dst[jj] = pk2(w2[base + (i0 & 3) + 8 * (i0 >> 2)],
                          w2[base + (i1 & 3) + 8 * (i1 >> 2)]);
        }
    }

    // ---- layer-1 A tile into LDS, fragment-linear (wave w packs mt=w) ------
    // lane (hi,l31) of fragment (mt,ks): row mt*32+l31, K-order cols
    // k<3 -> pw[row][k]; k==3 -> pb[row]; k>=4 -> pw[row][k-1]
    {
        const int mt = wid;
        const int hrow = mt * 32 + l31;
        const float* wrow = p + hrow * 63;
        const float bias  = p[8064 + hrow];
        char* dst = reinterpret_cast<char*>(awT) + mt * 4096 + lane * 16;
        #pragma unroll
        for (int ks = 0; ks < 4; ++ks) {
            U8 u;
            #pragma unroll
            for (int jj = 0; jj < 4; ++jj) {
                const int k0 = ks * 16 + hi * 8 + 2 * jj;
                const int k1 = k0 + 1;
                const float e0 = (k0 < 3) ? wrow[k0] : (k0 == 3 ? bias : wrow[k0 - 1]);
                const float e1 = (k1 < 3) ? wrow[k1] : (k1 == 3 ? bias : wrow[k1 - 1]);
                u.u[jj] = pk2(e0, e1);
            }
            *reinterpret_cast<uint4*>(dst + ks * 1024) = *reinterpret_cast<uint4*>(&u);
        }
    }

    f32x16 FZ;
    #pragma unroll
    for (int i = 0; i < 16; ++i) FZ[i] = 0.f;

    const float sb  = p[8320];
    const float cb0 = p[8786], cb1 = p[8787], cb2 = p[8788];
    const float* __restrict__ cwr  = p + 8321 + 128;
    const float* __restrict__ cwg  = p + 8321 + 155 + 128;
    const float* __restrict__ cwb2 = p + 8321 + 310 + 128;

    const int rayBlock = b * NRAY + chunk;
    float* __restrict__ rgbout = out + (long)NB * NRAY;
    const long pb0 = (long)(rayBlock + tid) * 3;
    const int hoff = hi * 64 + (l31 & 3) * 16;

    // ---- pos encoding, fragment-linear writes ------------------------------
    // this thread's ray lives at: block (tid>>5)*4 + g>>1, chunk = (g&1)*32 + l31
    // where group g covers K-order words 4g..4g+3 (rolling 4-word buffer).
    auto encode_row = [&](const float3 Pv) {
        char* wbase = encb + ((tid >> 5) * 4) * 1024 + (tid & 31) * 16;
        float s0 = __builtin_amdgcn_sinf(0.5f * Pv.x), c0 = __builtin_amdgcn_cosf(0.5f * Pv.x);
        float s1 = __builtin_amdgcn_sinf(0.5f * Pv.y), c1 = __builtin_amdgcn_cosf(0.5f * Pv.y);
        float s2 = __builtin_amdgcn_sinf(0.5f * Pv.z), c2 = __builtin_amdgcn_cosf(0.5f * Pv.z);
        unsigned wb[4];
        wb[0] = pk2(Pv.x, Pv.y);
        wb[1] = pk2(Pv.z, 1.0f);
        #pragma unroll
        for (int f = 0; f < 10; ++f) {
            const int w = 2 + 3 * f;
            #pragma unroll
            for (int k = 0; k < 3; ++k) {
                const int wk = w + k;
                wb[wk & 3] = (k == 0) ? pk2(s0, s1) : (k == 1) ? pk2(s2, c0) : pk2(c1, c2);
                if ((wk & 3) == 3) {
                    const int g = wk >> 2;
                    uint4 v; v.x = wb[0]; v.y = wb[1]; v.z = wb[2]; v.w = wb[3];
                    *reinterpret_cast<uint4*>(wbase + (g >> 1) * 1024 + (g & 1) * 512) = v;
                }
            }
            if (f < 9) {
                float t;
                t = 2.f * s0 * c0; c0 = fmaf(-2.f * s0, s0, 1.f); s0 = t;
                t = 2.f * s1 * c1; c1 = fmaf(-2.f * s1, s1, 1.f); s1 = t;
                t = 2.f * s2 * c2; c2 = fmaf(-2.f * s2, s2, 1.f); s2 = t;
            }
        }
    };

    // prologue: current inputs + iter-1 prefetch, encode iter-0
    float3 Pc = *reinterpret_cast<const float3*>(pos + pb0);
    float3 Dc = *reinterpret_cast<const float3*>(dir + pb0);
    encode_row(Pc);
    float3 Pn = *reinterpret_cast<const float3*>(pos + pb0 + 768);
    float3 Dn = *reinterpret_cast<const float3*>(dir + pb0 + 768);
    __syncthreads();    // awT + hawLds ready (enc blocks are wave-private)

    #pragma unroll 1
    for (int it = 0; it < NIT; ++it) {
        const int ray = rayBlock + it * 256 + tid;

        // ---- all 8 B-frag reads first, consecutive-address ------------------
        bf16x8 be0[4], be1[4];
        {
            const char* ebase = encb + (wid * 8) * 1024 + lane * 16;
            #pragma unroll
            for (int ks = 0; ks < 4; ++ks) {
                be0[ks] = *reinterpret_cast<const bf16x8*>(ebase + ks * 1024);
                be1[ks] = *reinterpret_cast<const bf16x8*>(ebase + (4 + ks) * 1024);
            }
        }

        // ---- encode(it+1): writes after reads (per-wave DS in-order) -------
        if (it < NIT - 1) encode_row(Pn);

        // ---- dir-tail partials: independent of MFMA -> latency filler ------
        float crd = 0.f, cgd = 0.f, cbd = 0.f;
        {
            float s0 = __builtin_amdgcn_sinf(0.5f * Dc.x), c0 = __builtin_amdgcn_cosf(0.5f * Dc.x);
            float s1 = __builtin_amdgcn_sinf(0.5f * Dc.y), c1 = __builtin_amdgcn_cosf(0.5f * Dc.y);
            float s2 = __builtin_amdgcn_sinf(0.5f * Dc.z), c2 = __builtin_amdgcn_cosf(0.5f * Dc.z);
            crd = fmaf(Dc.x, cwr[0], crd);  cgd = fmaf(Dc.x, cwg[0], cgd);  cbd = fmaf(Dc.x, cwb2[0], cbd);
            crd = fmaf(Dc.y, cwr[1], crd);  cgd = fmaf(Dc.y, cwg[1], cgd);  cbd = fmaf(Dc.y, cwb2[1], cbd);
            crd = fmaf(Dc.z, cwr[2], crd);  cgd = fmaf(Dc.z, cwg[2], cgd);  cbd = fmaf(Dc.z, cwb2[2], cbd);
            #pragma unroll
            for (int f = 0; f < 4; ++f) {
                const int jj = 3 + 6 * f;
                crd = fmaf(s0, cwr[jj+0], crd); cgd = fmaf(s0, cwg[jj+0], cgd); cbd = fmaf(s0, cwb2[jj+0], cbd);
                crd = fmaf(s1, cwr[jj+1], crd); cgd = fmaf(s1, cwg[jj+1], cgd); cbd = fmaf(s1, cwb2[jj+1], cbd);
                crd = fmaf(s2, cwr[jj+2], crd); cgd = fmaf(s2, cwg[jj+2], cgd); cbd = fmaf(s2, cwb2[jj+2], cbd);
                crd = fmaf(c0, cwr[jj+3], crd); cgd = fmaf(c0, cwg[jj+3], cgd); cbd = fmaf(c0, cwb2[jj+3], cbd);
                crd = fmaf(c1, cwr[jj+4], crd); cgd = fmaf(c1, cwg[jj+4], cgd); cbd = fmaf(c1, cwb2[jj+4], cbd);
                crd = fmaf(c2, cwr[jj+5], crd); cgd = fmaf(c2, cwg[jj+5], cgd); cbd = fmaf(c2, cwb2[jj+5], cbd);
                if (f < 3) {
                    float t;
                    t = 2.f * s0 * c0; c0 = fmaf(-2.f * s0, s0, 1.f); s0 = t;
                    t = 2.f * s1 * c1; c1 = fmaf(-2.f * s1, s1, 1.f); s1 = t;
                    t = 2.f * s2 * c2; c2 = fmaf(-2.f * s2, s2, 1.f); s2 = t;
                }
            }
        }

        // ---- prefetch inputs for it+2 (rotate below) ------------------------
        float3 Pn2, Dn2;
        if (it < NIT - 2) {
            Pn2 = *reinterpret_cast<const float3*>(pos + pb0 + (it + 2) * 768);
            Dn2 = *reinterpret_cast<const float3*>(dir + pb0 + (it + 2) * 768);
        }

        // ---- MFMA region: mt loop NOT unrolled (awf stays 16 regs) ---------
        __builtin_amdgcn_s_setprio(1);
        f32x16 hacc0 = FZ, hacc1 = FZ;
        #pragma unroll 1
        for (int mt = 0; mt < 4; ++mt) {
            const char* abase = awb + mt * 4096 + lane * 16;
            const bf16x8 awf0 = *reinterpret_cast<const bf16x8*>(abase);
            const bf16x8 awf1 = *reinterpret_cast<const bf16x8*>(abase + 1024);
            const bf16x8 awf2 = *reinterpret_cast<const bf16x8*>(abase + 2048);
            const bf16x8 awf3 = *reinterpret_cast<const bf16x8*>(abase + 3072);

            f32x16 a0 = MFMA(awf0, be0[0], FZ, 0, 0, 0);
            f32x16 a1 = MFMA(awf0, be1[0], FZ, 0, 0, 0);
            a0 = MFMA(awf1, be0[1], a0, 0, 0, 0);
            a1 = MFMA(awf1, be1[1], a1, 0, 0, 0);
            a0 = MFMA(awf2, be0[2], a0, 0, 0, 0);
            a1 = MFMA(awf2, be1[2], a1, 0, 0, 0);
            a0 = MFMA(awf3, be0[3], a0, 0, 0, 0);
            a1 = MFMA(awf3, be1[3], a1, 0, 0, 0);

            // relu -> pack own regs (pi-permuted head K: no cross-lane moves)
            #pragma unroll
            for (int t = 0; t < 2; ++t) {
                const int rb = t * 8;
                U8 u0, u1;
                #pragma unroll
                for (int jj = 0; jj < 4; ++jj) {
                    u0.u[jj] = pk2(fmaxf(a0[rb + 2 * jj], 0.f),
                                   fmaxf(a0[rb + 2 * jj + 1], 0.f));
                    u1.u[jj] = pk2(fmaxf(a1[rb + 2 * jj], 0.f),
                                   fmaxf(a1[rb + 2 * jj + 1], 0.f));
                }
                const bf16x8 hw = *reinterpret_cast<const bf16x8*>(
                    hawb + (2 * mt + t) * 128 + hoff);
                hacc0 = MFMA(hw, u0.v, hacc0, 0, 0, 0);
                hacc1 = MFMA(hw, u1.v, hacc1, 0, 0, 0);
            }
        }
        __builtin_amdgcn_s_setprio(0);

        // ---- per-ray tail: select + bias + dir partial + sigmoid -----------
        const float hv0 = hi ? hacc1[0] : hacc0[0];
        const float hv1 = hi ? hacc1[1] : hacc0[1];
        const float hv2 = hi ? hacc1[2] : hacc0[2];
        const float hv3 = hi ? hacc1[3] : hacc0[3];

        const float sig = hv0 + sb;
        float cr  = hv1 + cb0 + crd;
        float cg  = hv2 + cb1 + cgd;
        float cbl = hv3 + cb2 + cbd;

        cr  = 1.0f / (1.0f + __expf(-cr));
        cg  = 1.0f / (1.0f + __expf(-cg));
        cbl = 1.0f / (1.0f + __expf(-cbl));

        out[ray] = sig;
        float3 rgbv; rgbv.x = cr; rgbv.y = cg; rgbv.z = cbl;
        *reinterpret_cast<float3*>(rgbout + (long)ray * 3) = rgbv;

        Pn = Pn2; Dc = Dn; Dn = Dn2;
    }
}

extern "C" void kernel_launch(void* const* d_in, const int* in_sizes, int n_in,
                              void* d_out, int out_size, void* d_ws, size_t ws_size,
                              hipStream_t stream) {
    const float* pos    = (const float*)d_in[0];
    const float* dirs   = (const float*)d_in[1];
    const float* params = (const float*)d_in[2];
    float* out = (float*)d_out;

    dim3 grid(1024);   // 16 blocks/batch x 64 batches, 1024 rays each
    dim3 block(256);
    nerf_mfma_kernel<<<grid, block, 0, stream>>>(pos, dirs, params, out);
}

// Round 20
// 44.589 us; speedup vs baseline: 2.1115x; 1.0049x over previous
//
#include <hip/hip_runtime.h>
#include <hip/hip_bf16.h>

// BatchedNeRFMLP: B=64, N=16384, HID=128, POS_IN=63 (+bias col -> K=64), DIR_IN=27
// params per batch (TOTAL=8789 fp32):
//   pw [128][63] @0   pb[128]@8064   sw[128]@8192  sb@8320
//   cw [3][155] @8321 cb[3]@8786
// out: sigma (B*N) then rgb (B*N*3), fp32.
//
// r19 structure (44.8us best) MINUS s_setprio — clean A/B of the one knob
// never isolated. Mechanism: our prio-1 region contains the repack VALU
// bursts; a prio-1 wave's VALU outranks other waves' encode/dir VALU ->
// cross-wave starvation serializes waves (counters show wall ~3x per-wave
// critical path with all pipes <55% CU-aggregate). m190/T5: setprio only
// pays with phase-split wave roles; homogeneous waves are the anti-pattern.
//
// Carried from r19/r16:
//   - fragment-linear LDS (conflicts 1.63M -> 57K): block[frag]*1024+lane*16
//   - 3 blocks/CU via aw-in-LDS + mt unroll-1 (awf 16 regs live)  [r16]
//   - two nt tiles interleaved (2 independent L1 MFMA chains)     [r11]
//   - haw in LDS (1KB, broadcast reads)                           [r7]
//   - encode(it+1) after all frag reads (per-wave DS in-order)    [r5]
//   - dir-tail VALU before MFMA region (latency filler)           [r11]
//   - revolution-trig: sin(pi x) = builtin_sinf(0.5x)             [r9]
// Tripwire: WRITE_SIZE >> 16MB = spill = revert.

#define NB 64
#define NRAY 16384
#define NTOTAL 8789
#define NIT 4

typedef short bf16x8 __attribute__((ext_vector_type(8)));
typedef float f32x16 __attribute__((ext_vector_type(16)));

union U8 { unsigned u[4]; bf16x8 v; };

__device__ __forceinline__ unsigned pk2(float a, float b) {
    float2 t; t.x = a; t.y = b;
    __hip_bfloat162 h = __float22bfloat162_rn(t);   // v_cvt_pk_bf16_f32
    return *reinterpret_cast<unsigned*>(&h);
}

#define MFMA __builtin_amdgcn_mfma_f32_32x32x16_bf16

__global__ __launch_bounds__(256, 3) void nerf_mfma_kernel(
    const float* __restrict__ pos,
    const float* __restrict__ dir,
    const float* __restrict__ params,
    float* __restrict__ out)
{
    const int tid  = threadIdx.x;
    const int lane = tid & 63;
    const int wid  = tid >> 6;
    const int hi   = lane >> 5;
    const int l31  = lane & 31;

    const int b     = blockIdx.x >> 4;          // 16 blocks per batch
    const int chunk = (blockIdx.x & 15) << 10;  // 1024 rays per block
    const float* __restrict__ p = params + b * NTOTAL;

    // fragment-linear tiles: [block][chunk16B]; 1024B per fragment-block
    __shared__ uint4 encs[2048];                // 32 blocks x 64 chunks = 32KB
    __shared__ uint4 awT[1024];                 // 16 blocks x 64 chunks = 16KB
    __shared__ unsigned hawLds[256];            // [s][hi][r][4 words] = 1KB
    char* encb = reinterpret_cast<char*>(encs);
    const char* awb  = reinterpret_cast<const char*>(awT);
    const char* hawb = reinterpret_cast<const char*>(hawLds);

    // ---- head-weight fragments into LDS (one-time, 64 threads) ------------
    // K permuted: slot(s,hh,i) -> h = 32*(s>>1)+16*(s&1)+4*hh+(i&3)+8*(i>>2)
    if (tid < 64) {
        const int s  = tid & 7;
        const int hh = (tid >> 3) & 1;
        const int r  = tid >> 4;                // 0=sigma(sw), 1..3 = cw rows
        const float* w2 = (r == 0) ? (p + 8192) : (p + 8321 + (r - 1) * 155);
        const int base = 32 * (s >> 1) + 16 * (s & 1) + 4 * hh;
        unsigned* dst = &hawLds[(((s << 1) + hh) * 4 + r) * 4];
        #pragma unroll
        for (int jj = 0; jj < 4; ++jj) {
            const int i0 = 2 * jj, i1 = 2 * jj + 1;
            dst[jj] = pk2(w2[base + (i0 & 3) + 8 * (i0 >> 2)],
                          w2[base + (i1 & 3) + 8 * (i1 >> 2)]);
        }
    }

    // ---- layer-1 A tile into LDS, fragment-linear (wave w packs mt=w) ------
    // lane (hi,l31) of fragment (mt,ks): row mt*32+l31, K-order cols
    // k<3 -> pw[row][k]; k==3 -> pb[row]; k>=4 -> pw[row][k-1]
    {
        const int mt = wid;
        const int hrow = mt * 32 + l31;
        const float* wrow = p + hrow * 63;
        const float bias  = p[8064 + hrow];
        char* dst = reinterpret_cast<char*>(awT) + mt * 4096 + lane * 16;
        #pragma unroll
        for (int ks = 0; ks < 4; ++ks) {
            U8 u;
            #pragma unroll
            for (int jj = 0; jj < 4; ++jj) {
                const int k0 = ks * 16 + hi * 8 + 2 * jj;
                const int k1 = k0 + 1;
                const float e0 = (k0 < 3) ? wrow[k0] : (k0 == 3 ? bias : wrow[k0 - 1]);
                const float e1 = (k1 < 3) ? wrow[k1] : (k1 == 3 ? bias : wrow[k1 - 1]);
                u.u[jj] = pk2(e0, e1);
            }
            *reinterpret_cast<uint4*>(dst + ks * 1024) = *reinterpret_cast<uint4*>(&u);
        }
    }

    f32x16 FZ;
    #pragma unroll
    for (int i = 0; i < 16; ++i) FZ[i] = 0.f;

    const float sb  = p[8320];
    const float cb0 = p[8786], cb1 = p[8787], cb2 = p[8788];
    const float* __restrict__ cwr  = p + 8321 + 128;
    const float* __restrict__ cwg  = p + 8321 + 155 + 128;
    const float* __restrict__ cwb2 = p + 8321 + 310 + 128;

    const int rayBlock = b * NRAY + chunk;
    float* __restrict__ rgbout = out + (long)NB * NRAY;
    const long pb0 = (long)(rayBlock + tid) * 3;
    const int hoff = hi * 64 + (l31 & 3) * 16;

    // ---- pos encoding, fragment-linear writes ------------------------------
    // this thread's ray lives at: block (tid>>5)*4 + g>>1, chunk = (g&1)*32 + l31
    // where group g covers K-order words 4g..4g+3 (rolling 4-word buffer).
    auto encode_row = [&](const float3 Pv) {
        char* wbase = encb + ((tid >> 5) * 4) * 1024 + (tid & 31) * 16;
        float s0 = __builtin_amdgcn_sinf(0.5f * Pv.x), c0 = __builtin_amdgcn_cosf(0.5f * Pv.x);
        float s1 = __builtin_amdgcn_sinf(0.5f * Pv.y), c1 = __builtin_amdgcn_cosf(0.5f * Pv.y);
        float s2 = __builtin_amdgcn_sinf(0.5f * Pv.z), c2 = __builtin_amdgcn_cosf(0.5f * Pv.z);
        unsigned wb[4];
        wb[0] = pk2(Pv.x, Pv.y);
        wb[1] = pk2(Pv.z, 1.0f);
        #pragma unroll
        for (int f = 0; f < 10; ++f) {
            const int w = 2 + 3 * f;
            #pragma unroll
            for (int k = 0; k < 3; ++k) {
                const int wk = w + k;
                wb[wk & 3] = (k == 0) ? pk2(s0, s1) : (k == 1) ? pk2(s2, c0) : pk2(c1, c2);
                if ((wk & 3) == 3) {
                    const int g = wk >> 2;
                    uint4 v; v.x = wb[0]; v.y = wb[1]; v.z = wb[2]; v.w = wb[3];
                    *reinterpret_cast<uint4*>(wbase + (g >> 1) * 1024 + (g & 1) * 512) = v;
                }
            }
            if (f < 9) {
                float t;
                t = 2.f * s0 * c0; c0 = fmaf(-2.f * s0, s0, 1.f); s0 = t;
                t = 2.f * s1 * c1; c1 = fmaf(-2.f * s1, s1, 1.f); s1 = t;
                t = 2.f * s2 * c2; c2 = fmaf(-2.f * s2, s2, 1.f); s2 = t;
            }
        }
    };

    // prologue: current inputs + iter-1 prefetch, encode iter-0
    float3 Pc = *reinterpret_cast<const float3*>(pos + pb0);
    float3 Dc = *reinterpret_cast<const float3*>(dir + pb0);
    encode_row(Pc);
    float3 Pn = *reinterpret_cast<const float3*>(pos + pb0 + 768);
    float3 Dn = *reinterpret_cast<const float3*>(dir + pb0 + 768);
    __syncthreads();    // awT + hawLds ready (enc blocks are wave-private)

    #pragma unroll 1
    for (int it = 0; it < NIT; ++it) {
        const int ray = rayBlock + it * 256 + tid;

        // ---- all 8 B-frag reads first, consecutive-address ------------------
        bf16x8 be0[4], be1[4];
        {
            const char* ebase = encb + (wid * 8) * 1024 + lane * 16;
            #pragma unroll
            for (int ks = 0; ks < 4; ++ks) {
                be0[ks] = *reinterpret_cast<const bf16x8*>(ebase + ks * 1024);
                be1[ks] = *reinterpret_cast<const bf16x8*>(ebase + (4 + ks) * 1024);
            }
        }

        // ---- encode(it+1): writes after reads (per-wave DS in-order) -------
        if (it < NIT - 1) encode_row(Pn);

        // ---- dir-tail partials: independent of MFMA -> latency filler ------
        float crd = 0.f, cgd = 0.f, cbd = 0.f;
        {
            float s0 = __builtin_amdgcn_sinf(0.5f * Dc.x), c0 = __builtin_amdgcn_cosf(0.5f * Dc.x);
            float s1 = __builtin_amdgcn_sinf(0.5f * Dc.y), c1 = __builtin_amdgcn_cosf(0.5f * Dc.y);
            float s2 = __builtin_amdgcn_sinf(0.5f * Dc.z), c2 = __builtin_amdgcn_cosf(0.5f * Dc.z);
            crd = fmaf(Dc.x, cwr[0], crd);  cgd = fmaf(Dc.x, cwg[0], cgd);  cbd = fmaf(Dc.x, cwb2[0], cbd);
            crd = fmaf(Dc.y, cwr[1], crd);  cgd = fmaf(Dc.y, cwg[1], cgd);  cbd = fmaf(Dc.y, cwb2[1], cbd);
            crd = fmaf(Dc.z, cwr[2], crd);  cgd = fmaf(Dc.z, cwg[2], cgd);  cbd = fmaf(Dc.z, cwb2[2], cbd);
            #pragma unroll
            for (int f = 0; f < 4; ++f) {
                const int jj = 3 + 6 * f;
                crd = fmaf(s0, cwr[jj+0], crd); cgd = fmaf(s0, cwg[jj+0], cgd); cbd = fmaf(s0, cwb2[jj+0], cbd);
                crd = fmaf(s1, cwr[jj+1], crd); cgd = fmaf(s1, cwg[jj+1], cgd); cbd = fmaf(s1, cwb2[jj+1], cbd);
                crd = fmaf(s2, cwr[jj+2], crd); cgd = fmaf(s2, cwg[jj+2], cgd); cbd = fmaf(s2, cwb2[jj+2], cbd);
                crd = fmaf(c0, cwr[jj+3], crd); cgd = fmaf(c0, cwg[jj+3], cgd); cbd = fmaf(c0, cwb2[jj+3], cbd);
                crd = fmaf(c1, cwr[jj+4], crd); cgd = fmaf(c1, cwg[jj+4], cgd); cbd = fmaf(c1, cwb2[jj+4], cbd);
                crd = fmaf(c2, cwr[jj+5], crd); cgd = fmaf(c2, cwg[jj+5], cgd); cbd = fmaf(c2, cwb2[jj+5], cbd);
                if (f < 3) {
                    float t;
                    t = 2.f * s0 * c0; c0 = fmaf(-2.f * s0, s0, 1.f); s0 = t;
                    t = 2.f * s1 * c1; c1 = fmaf(-2.f * s1, s1, 1.f); s1 = t;
                    t = 2.f * s2 * c2; c2 = fmaf(-2.f * s2, s2, 1.f); s2 = t;
                }
            }
        }

        // ---- prefetch inputs for it+2 (rotate below) ------------------------
        float3 Pn2, Dn2;
        if (it < NIT - 2) {
            Pn2 = *reinterpret_cast<const float3*>(pos + pb0 + (it + 2) * 768);
            Dn2 = *reinterpret_cast<const float3*>(dir + pb0 + (it + 2) * 768);
        }

        // ---- MFMA region: mt loop NOT unrolled (awf stays 16 regs) ---------
        // NO s_setprio: homogeneous waves -> priority causes cross-wave VALU
        // starvation (repack bursts at prio 1 starve other waves' encode VALU).
        f32x16 hacc0 = FZ, hacc1 = FZ;
        #pragma unroll 1
        for (int mt = 0; mt < 4; ++mt) {
            const char* abase = awb + mt * 4096 + lane * 16;
            const bf16x8 awf0 = *reinterpret_cast<const bf16x8*>(abase);
            const bf16x8 awf1 = *reinterpret_cast<const bf16x8*>(abase + 1024);
            const bf16x8 awf2 = *reinterpret_cast<const bf16x8*>(abase + 2048);
            const bf16x8 awf3 = *reinterpret_cast<const bf16x8*>(abase + 3072);

            f32x16 a0 = MFMA(awf0, be0[0], FZ, 0, 0, 0);
            f32x16 a1 = MFMA(awf0, be1[0], FZ, 0, 0, 0);
            a0 = MFMA(awf1, be0[1], a0, 0, 0, 0);
            a1 = MFMA(awf1, be1[1], a1, 0, 0, 0);
            a0 = MFMA(awf2, be0[2], a0, 0, 0, 0);
            a1 = MFMA(awf2, be1[2], a1, 0, 0, 0);
            a0 = MFMA(awf3, be0[3], a0, 0, 0, 0);
            a1 = MFMA(awf3, be1[3], a1, 0, 0, 0);

            // relu -> pack own regs (pi-permuted head K: no cross-lane moves)
            #pragma unroll
            for (int t = 0; t < 2; ++t) {
                const int rb = t * 8;
                U8 u0, u1;
                #pragma unroll
                for (int jj = 0; jj < 4; ++jj) {
                    u0.u[jj] = pk2(fmaxf(a0[rb + 2 * jj], 0.f),
                                   fmaxf(a0[rb + 2 * jj + 1], 0.f));
                    u1.u[jj] = pk2(fmaxf(a1[rb + 2 * jj], 0.f),
                                   fmaxf(a1[rb + 2 * jj + 1], 0.f));
                }
                const bf16x8 hw = *reinterpret_cast<const bf16x8*>(
                    hawb + (2 * mt + t) * 128 + hoff);
                hacc0 = MFMA(hw, u0.v, hacc0, 0, 0, 0);
                hacc1 = MFMA(hw, u1.v, hacc1, 0, 0, 0);
            }
        }

        // ---- per-ray tail: select + bias + dir partial + sigmoid -----------
        const float hv0 = hi ? hacc1[0] : hacc0[0];
        const float hv1 = hi ? hacc1[1] : hacc0[1];
        const float hv2 = hi ? hacc1[2] : hacc0[2];
        const float hv3 = hi ? hacc1[3] : hacc0[3];

        const float sig = hv0 + sb;
        float cr  = hv1 + cb0 + crd;
        float cg  = hv2 + cb1 + cgd;
        float cbl = hv3 + cb2 + cbd;

        cr  = 1.0f / (1.0f + __expf(-cr));
        cg  = 1.0f / (1.0f + __expf(-cg));
        cbl = 1.0f / (1.0f + __expf(-cbl));

        out[ray] = sig;
        float3 rgbv; rgbv.x = cr; rgbv.y = cg; rgbv.z = cbl;
        *reinterpret_cast<float3*>(rgbout + (long)ray * 3) = rgbv;

        Pn = Pn2; Dc = Dn; Dn = Dn2;
    }
}

extern "C" void kernel_launch(void* const* d_in, const int* in_sizes, int n_in,
                              void* d_out, int out_size, void* d_ws, size_t ws_size,
                              hipStream_t stream) {
    const float* pos    = (const float*)d_in[0];
    const float* dirs   = (const float*)d_in[1];
    const float* params = (const float*)d_in[2];
    float* out = (float*)d_out;

    dim3 grid(1024);   // 16 blocks/batch x 64 batches, 1024 rays each
    dim3 block(256);
    nerf_mfma_kernel<<<grid, block, 0, stream>>>(pos, dirs, params, out);
}